// Round 2
// baseline (645.294 us; speedup 1.0000x reference)
//
#include <hip/hip_runtime.h>
#include <math.h>

#define N_NODES 50000
#define N_EDGES 800000
#define NPW 16  // nodes per wave in layer/head kernels

// ---------- helpers ----------
__device__ __forceinline__ float bcast(float v, int lane) {
  return __int_as_float(__builtin_amdgcn_readlane(__float_as_int(v), lane));
}
__device__ __forceinline__ unsigned short f2bf(float f) {  // RNE f32->bf16
  unsigned int u = __float_as_uint(f);
  u += 0x7FFFu + ((u >> 16) & 1u);
  return (unsigned short)(u >> 16);
}
__device__ __forceinline__ float bf2f(unsigned short s) {
  return __uint_as_float(((unsigned int)s) << 16);
}

// ---------- 1. input projection: h = relu(x @ Wp + bp); writes f32 + bf16 ----------
__global__ __launch_bounds__(256) void k_proj(const float* __restrict__ x,
                                              const float* __restrict__ Wp,
                                              const float* __restrict__ bp,
                                              float* __restrict__ h,
                                              unsigned short* __restrict__ hb) {
  int idx = blockIdx.x * 256 + threadIdx.x;
  int n = idx >> 6, j = idx & 63;
  if (n >= N_NODES) return;
  float acc = bp[j];
#pragma unroll
  for (int k = 0; k < 10; k++) acc += x[n * 10 + k] * Wp[k * 64 + j];
  float r = fmaxf(acc, 0.f);
  h[n * 64 + j] = r;
  hb[n * 64 + j] = f2bf(r);
}

// ---------- 2. CSR build ----------
__global__ __launch_bounds__(256) void k_hist(const int* __restrict__ ei, int* __restrict__ deg) {
  int e = blockIdx.x * 256 + threadIdx.x;
  if (e >= N_EDGES) return;
  atomicAdd(&deg[ei[N_EDGES + e]], 1);
}

__global__ __launch_bounds__(256) void k_scan1(const int* __restrict__ deg,
                                               int* __restrict__ offs,
                                               int* __restrict__ bsums) {
  __shared__ int sm[256];
  int i = blockIdx.x * 256 + threadIdx.x;
  int v = (i < N_NODES) ? deg[i] : 0;
  sm[threadIdx.x] = v;
  __syncthreads();
#pragma unroll
  for (int off = 1; off < 256; off <<= 1) {
    int t = (threadIdx.x >= off) ? sm[threadIdx.x - off] : 0;
    __syncthreads();
    sm[threadIdx.x] += t;
    __syncthreads();
  }
  if (i < N_NODES) offs[i] = sm[threadIdx.x] - v;  // exclusive
  if (threadIdx.x == 255) bsums[blockIdx.x] = sm[255];
}

__global__ __launch_bounds__(256) void k_scan2(int* __restrict__ bsums, int nb) {
  __shared__ int sm[256];
  int t = threadIdx.x;
  int v = (t < nb) ? bsums[t] : 0;
  sm[t] = v;
  __syncthreads();
#pragma unroll
  for (int off = 1; off < 256; off <<= 1) {
    int u = (t >= off) ? sm[t - off] : 0;
    __syncthreads();
    sm[t] += u;
    __syncthreads();
  }
  if (t < nb) bsums[t] = sm[t] - v;  // exclusive
}

__global__ __launch_bounds__(256) void k_scan3(int* __restrict__ offs,
                                               const int* __restrict__ bsums,
                                               int* __restrict__ cursor) {
  int i = blockIdx.x * 256 + threadIdx.x;
  if (i >= N_NODES) return;
  int o = offs[i] + bsums[blockIdx.x];
  offs[i] = o;
  cursor[i] = o;
}

// fill CSR; fuse the 3-layer edge MLP. 8B record:
//   x = src(17 bits) | q0<<17 ; y = q1 | q2<<15   (q = round(w*32767), 15-bit)
__global__ __launch_bounds__(256) void k_fill(const int* __restrict__ ei,
                                              const float* __restrict__ ea,
                                              const float* __restrict__ ew1,
                                              const float* __restrict__ eb1,
                                              const float* __restrict__ ew2,
                                              const float* __restrict__ eb2,
                                              int* __restrict__ cursor,
                                              uint2* __restrict__ csr) {
  int e = blockIdx.x * 256 + threadIdx.x;
  if (e >= N_EDGES) return;
  int s = ei[e];
  int d = ei[N_EDGES + e];
  float a0 = ea[e * 3 + 0], a1 = ea[e * 3 + 1], a2 = ea[e * 3 + 2];
  int q[3];
#pragma unroll
  for (int l = 0; l < 3; l++) {
    float z = eb2[l];
#pragma unroll
    for (int t = 0; t < 16; t++) {
      float hd = a0 * ew1[l * 48 + t] + a1 * ew1[l * 48 + 16 + t] +
                 a2 * ew1[l * 48 + 32 + t] + eb1[l * 16 + t];
      z += fmaxf(hd, 0.f) * ew2[l * 16 + t];
    }
    float w = 1.f / (1.f + __expf(-z));
    q[l] = __float2int_rn(w * 32767.f);
  }
  unsigned int w0 = (unsigned int)s | ((unsigned int)q[0] << 17);
  unsigned int w1 = (unsigned int)q[1] | ((unsigned int)q[2] << 15);
  int p = atomicAdd(&cursor[d], 1);
  csr[p] = make_uint2(w0, w1);
}

template <int LI>
__device__ __forceinline__ float decw(uint2 c) {
  unsigned int q = (LI == 0) ? (c.x >> 17) : (LI == 1) ? (c.y & 0x7FFFu) : (c.y >> 15);
  return (float)q * (1.f / 32767.f);
}

// ---------- 3. fused layer: gather-aggregate + node MLP + residual + LayerNorm ----------
template <int LI>
__global__ __launch_bounds__(256, 2) void k_layer(const uint2* __restrict__ csr,
                                                  const int* __restrict__ offs,
                                                  const int* __restrict__ deg,
                                                  const unsigned short* __restrict__ hbin,
                                                  const float* __restrict__ hin,
                                                  const float* __restrict__ nw,
                                                  const float* __restrict__ nb,
                                                  const float* __restrict__ g,
                                                  const float* __restrict__ b,
                                                  float* __restrict__ hout,
                                                  unsigned short* __restrict__ hbout) {
  int j = threadIdx.x & 63;
  int gw = (blockIdx.x * 256 + threadIdx.x) >> 6;
  float wreg[128];
#pragma unroll
  for (int k = 0; k < 128; k++) wreg[k] = nw[k * 64 + j];  // lane j = output col j
  float nbj = nb[j], gj = g[j], bj = b[j];
  int n0 = gw * NPW;
  for (int n = n0; n < n0 + NPW; ++n) {
    if (n >= N_NODES) break;
    int start = offs[n];
    int d = deg[n];
    float acc = 0.f, wsum = 0.f;
    int i = 0;
    for (; i + 4 <= d; i += 4) {
      uint2 c0 = csr[start + i + 0];
      uint2 c1 = csr[start + i + 1];
      uint2 c2 = csr[start + i + 2];
      uint2 c3 = csr[start + i + 3];
      float w0 = decw<LI>(c0), w1 = decw<LI>(c1), w2 = decw<LI>(c2), w3 = decw<LI>(c3);
      float h0 = bf2f(hbin[(c0.x & 0x1FFFFu) * 64 + j]);
      float h1 = bf2f(hbin[(c1.x & 0x1FFFFu) * 64 + j]);
      float h2 = bf2f(hbin[(c2.x & 0x1FFFFu) * 64 + j]);
      float h3 = bf2f(hbin[(c3.x & 0x1FFFFu) * 64 + j]);
      acc += h0 * w0 + h1 * w1 + h2 * w2 + h3 * w3;
      wsum += w0 + w1 + w2 + w3;
    }
    for (; i < d; ++i) {
      uint2 c = csr[start + i];
      float w = decw<LI>(c);
      acc += bf2f(hbin[(c.x & 0x1FFFFu) * 64 + j]) * w;
      wsum += w;
    }
    float av = acc / fmaxf(wsum, 1e-12f);
    float hv = hin[n * 64 + j];
    float z = nbj;
#pragma unroll
    for (int k = 0; k < 64; k++) z += bcast(hv, k) * wreg[k];
#pragma unroll
    for (int k = 0; k < 64; k++) z += bcast(av, k) * wreg[64 + k];
    float r = hv + fmaxf(z, 0.f);
    float s = r;
#pragma unroll
    for (int off = 32; off; off >>= 1) s += __shfl_xor(s, off);
    float mu = s * (1.f / 64.f);
    float dd = r - mu;
    float v2 = dd * dd;
#pragma unroll
    for (int off = 32; off; off >>= 1) v2 += __shfl_xor(v2, off);
    float rs = rsqrtf(v2 * (1.f / 64.f) + 1e-5f);
    float o = dd * rs * gj + bj;
    hout[n * 64 + j] = o;
    hbout[n * 64 + j] = f2bf(o);
  }
}

// ---------- 4. head: out = relu(h@hw1+hb1)@hw2 + hb2 ----------
__global__ __launch_bounds__(256, 2) void k_head(const float* __restrict__ hw1,
                                                 const float* __restrict__ hb1,
                                                 const float* __restrict__ hw2,
                                                 const float* __restrict__ hb2,
                                                 const float* __restrict__ hin,
                                                 float* __restrict__ out) {
  int j = threadIdx.x & 63;
  int jj = j & 31;
  int gw = (blockIdx.x * 256 + threadIdx.x) >> 6;
  float w1[64];
#pragma unroll
  for (int k = 0; k < 64; k++) w1[k] = hw1[k * 32 + jj];
  float hb1j = hb1[jj];
  float hw2j = hw2[jj];
  float hb2v = hb2[0];
  int n0 = gw * NPW;
  for (int n = n0; n < n0 + NPW; ++n) {
    if (n >= N_NODES) break;
    float hv = hin[n * 64 + j];
    float acc = hb1j;
#pragma unroll
    for (int k = 0; k < 64; k++) acc += bcast(hv, k) * w1[k];
    float z = fmaxf(acc, 0.f) * hw2j;
    if (j >= 32) z = 0.f;  // upper 32 lanes duplicate lower-half columns
#pragma unroll
    for (int off = 32; off; off >>= 1) z += __shfl_xor(z, off);
    if (j == 0) out[n] = z + hb2v;
  }
}

// ---------- launch ----------
static inline size_t align256(size_t x) { return (x + 255) & ~size_t(255); }

extern "C" void kernel_launch(void* const* d_in, const int* in_sizes, int n_in,
                              void* d_out, int out_size, void* d_ws, size_t ws_size,
                              hipStream_t stream) {
  const float* x   = (const float*)d_in[0];
  const int*   ei  = (const int*)d_in[1];
  const float* ea  = (const float*)d_in[2];
  const float* Wp  = (const float*)d_in[3];
  const float* bp  = (const float*)d_in[4];
  const float* ew1 = (const float*)d_in[5];
  const float* eb1 = (const float*)d_in[6];
  const float* ew2 = (const float*)d_in[7];
  const float* eb2 = (const float*)d_in[8];
  const float* nw  = (const float*)d_in[9];
  const float* nb  = (const float*)d_in[10];
  const float* lng = (const float*)d_in[11];
  const float* lnb = (const float*)d_in[12];
  const float* hw1 = (const float*)d_in[13];
  const float* hb1 = (const float*)d_in[14];
  const float* hw2 = (const float*)d_in[15];
  const float* hb2 = (const float*)d_in[16];
  float* out = (float*)d_out;

  char* ws = (char*)d_ws;
  size_t off = 0;
  float* h0f = (float*)(ws + off); off = align256(off + (size_t)N_NODES * 64 * 4);
  float* h1f = (float*)(ws + off); off = align256(off + (size_t)N_NODES * 64 * 4);
  unsigned short* hb0 = (unsigned short*)(ws + off); off = align256(off + (size_t)N_NODES * 64 * 2);
  unsigned short* hb1b = (unsigned short*)(ws + off); off = align256(off + (size_t)N_NODES * 64 * 2);
  uint2* csr = (uint2*)(ws + off); off = align256(off + (size_t)N_EDGES * 8);
  int* deg    = (int*)(ws + off); off = align256(off + (size_t)N_NODES * 4);
  int* offs   = (int*)(ws + off); off = align256(off + (size_t)N_NODES * 4);
  int* cursor = (int*)(ws + off); off = align256(off + (size_t)N_NODES * 4);
  int* bsums  = (int*)(ws + off); off = align256(off + 1024);

  const int NB_SCAN = (N_NODES + 255) / 256;  // 196

  hipMemsetAsync(deg, 0, (size_t)N_NODES * 4, stream);

  k_proj<<<(N_NODES * 64 + 255) / 256, 256, 0, stream>>>(x, Wp, bp, h0f, hb0);
  k_hist<<<(N_EDGES + 255) / 256, 256, 0, stream>>>(ei, deg);
  k_scan1<<<NB_SCAN, 256, 0, stream>>>(deg, offs, bsums);
  k_scan2<<<1, 256, 0, stream>>>(bsums, NB_SCAN);
  k_scan3<<<NB_SCAN, 256, 0, stream>>>(offs, bsums, cursor);
  k_fill<<<(N_EDGES + 255) / 256, 256, 0, stream>>>(ei, ea, ew1, eb1, ew2, eb2, cursor, csr);

  const int layerGrid = ((N_NODES + NPW - 1) / NPW + 3) / 4;  // 4 waves/block

  k_layer<0><<<layerGrid, 256, 0, stream>>>(csr, offs, deg, hb0, h0f,
                                            nw + 0 * 8192, nb + 0 * 64, lng + 0 * 64, lnb + 0 * 64,
                                            h1f, hb1b);
  k_layer<1><<<layerGrid, 256, 0, stream>>>(csr, offs, deg, hb1b, h1f,
                                            nw + 1 * 8192, nb + 1 * 64, lng + 1 * 64, lnb + 1 * 64,
                                            h0f, hb0);
  k_layer<2><<<layerGrid, 256, 0, stream>>>(csr, offs, deg, hb0, h0f,
                                            nw + 2 * 8192, nb + 2 * 64, lng + 2 * 64, lnb + 2 * 64,
                                            h1f, hb1b);

  k_head<<<layerGrid, 256, 0, stream>>>(hw1, hb1, hw2, hb2, h1f, out);
}

// Round 3
// 456.866 us; speedup vs baseline: 1.4124x; 1.4124x over previous
//
#include <hip/hip_runtime.h>
#include <math.h>

#define N_NODES 50000
#define N_EDGES 800000
#define NPW 16  // nodes per wave in mlp/head kernels

// ---------- helpers ----------
__device__ __forceinline__ float bcast(float v, int lane) {
  return __int_as_float(__builtin_amdgcn_readlane(__float_as_int(v), lane));
}
__device__ __forceinline__ unsigned short f2bf(float f) {  // RNE f32->bf16
  unsigned int u = __float_as_uint(f);
  u += 0x7FFFu + ((u >> 16) & 1u);
  return (unsigned short)(u >> 16);
}
__device__ __forceinline__ float bf2f(unsigned short s) {
  return __uint_as_float(((unsigned int)s) << 16);
}

// ---------- 1. input projection: h = relu(x @ Wp + bp); writes f32 + bf16 ----------
__global__ __launch_bounds__(256) void k_proj(const float* __restrict__ x,
                                              const float* __restrict__ Wp,
                                              const float* __restrict__ bp,
                                              float* __restrict__ h,
                                              unsigned short* __restrict__ hb) {
  int idx = blockIdx.x * 256 + threadIdx.x;
  int n = idx >> 6, j = idx & 63;
  if (n >= N_NODES) return;
  float acc = bp[j];
#pragma unroll
  for (int k = 0; k < 10; k++) acc += x[n * 10 + k] * Wp[k * 64 + j];
  float r = fmaxf(acc, 0.f);
  h[n * 64 + j] = r;
  hb[n * 64 + j] = f2bf(r);
}

// ---------- 2. CSR build ----------
__global__ __launch_bounds__(256) void k_hist(const int* __restrict__ ei, int* __restrict__ deg) {
  int e = blockIdx.x * 256 + threadIdx.x;
  if (e >= N_EDGES) return;
  atomicAdd(&deg[ei[N_EDGES + e]], 1);
}

__global__ __launch_bounds__(256) void k_scan1(const int* __restrict__ deg,
                                               int* __restrict__ offs,
                                               int* __restrict__ bsums) {
  __shared__ int sm[256];
  int i = blockIdx.x * 256 + threadIdx.x;
  int v = (i < N_NODES) ? deg[i] : 0;
  sm[threadIdx.x] = v;
  __syncthreads();
#pragma unroll
  for (int off = 1; off < 256; off <<= 1) {
    int t = (threadIdx.x >= off) ? sm[threadIdx.x - off] : 0;
    __syncthreads();
    sm[threadIdx.x] += t;
    __syncthreads();
  }
  if (i < N_NODES) offs[i] = sm[threadIdx.x] - v;  // exclusive
  if (threadIdx.x == 255) bsums[blockIdx.x] = sm[255];
}

__global__ __launch_bounds__(256) void k_scan2(int* __restrict__ bsums, int nb) {
  __shared__ int sm[256];
  int t = threadIdx.x;
  int v = (t < nb) ? bsums[t] : 0;
  sm[t] = v;
  __syncthreads();
#pragma unroll
  for (int off = 1; off < 256; off <<= 1) {
    int u = (t >= off) ? sm[t - off] : 0;
    __syncthreads();
    sm[t] += u;
    __syncthreads();
  }
  if (t < nb) bsums[t] = sm[t] - v;  // exclusive
}

__global__ __launch_bounds__(256) void k_scan3(int* __restrict__ offs,
                                               const int* __restrict__ bsums,
                                               int* __restrict__ cursor) {
  int i = blockIdx.x * 256 + threadIdx.x;
  if (i >= N_NODES) return;
  int o = offs[i] + bsums[blockIdx.x];
  offs[i] = o;
  cursor[i] = o;
}

// fill CSR; fuse the 3-layer edge MLP. 8B record:
//   x = src(17 bits) | q0<<17 ; y = q1 | q2<<15   (q = round(w*32767), 15-bit)
__global__ __launch_bounds__(256) void k_fill(const int* __restrict__ ei,
                                              const float* __restrict__ ea,
                                              const float* __restrict__ ew1,
                                              const float* __restrict__ eb1,
                                              const float* __restrict__ ew2,
                                              const float* __restrict__ eb2,
                                              int* __restrict__ cursor,
                                              uint2* __restrict__ csr) {
  int e = blockIdx.x * 256 + threadIdx.x;
  if (e >= N_EDGES) return;
  int s = ei[e];
  int d = ei[N_EDGES + e];
  float a0 = ea[e * 3 + 0], a1 = ea[e * 3 + 1], a2 = ea[e * 3 + 2];
  int q[3];
#pragma unroll
  for (int l = 0; l < 3; l++) {
    float z = eb2[l];
#pragma unroll
    for (int t = 0; t < 16; t++) {
      float hd = a0 * ew1[l * 48 + t] + a1 * ew1[l * 48 + 16 + t] +
                 a2 * ew1[l * 48 + 32 + t] + eb1[l * 16 + t];
      z += fmaxf(hd, 0.f) * ew2[l * 16 + t];
    }
    float w = 1.f / (1.f + __expf(-z));
    q[l] = __float2int_rn(w * 32767.f);
  }
  unsigned int w0 = (unsigned int)s | ((unsigned int)q[0] << 17);
  unsigned int w1 = (unsigned int)q[1] | ((unsigned int)q[2] << 15);
  int p = atomicAdd(&cursor[d], 1);
  csr[p] = make_uint2(w0, w1);
}

template <int LI>
__device__ __forceinline__ float decw(uint2 c) {
  unsigned int q = (LI == 0) ? (c.x >> 17) : (LI == 1) ? (c.y & 0x7FFFu) : (c.y >> 15);
  return (float)q * (1.f / 32767.f);
}

// ---------- 3. aggregation: wave per node, lane = feature, bf16 gather ----------
template <int LI>
__global__ __launch_bounds__(256, 4) void k_agg(const uint2* __restrict__ csr,
                                                const int* __restrict__ offs,
                                                const int* __restrict__ deg,
                                                const unsigned short* __restrict__ hbin,
                                                float* __restrict__ agg) {
  int n = (blockIdx.x * 256 + threadIdx.x) >> 6;
  int j = threadIdx.x & 63;
  if (n >= N_NODES) return;
  int start = offs[n];
  int d = deg[n];
  float acc = 0.f, wsum = 0.f;
  int i = 0;
  for (; i + 4 <= d; i += 4) {
    uint2 c0 = csr[start + i + 0];
    uint2 c1 = csr[start + i + 1];
    uint2 c2 = csr[start + i + 2];
    uint2 c3 = csr[start + i + 3];
    float w0 = decw<LI>(c0), w1 = decw<LI>(c1), w2 = decw<LI>(c2), w3 = decw<LI>(c3);
    float h0 = bf2f(hbin[(c0.x & 0x1FFFFu) * 64 + j]);
    float h1 = bf2f(hbin[(c1.x & 0x1FFFFu) * 64 + j]);
    float h2 = bf2f(hbin[(c2.x & 0x1FFFFu) * 64 + j]);
    float h3 = bf2f(hbin[(c3.x & 0x1FFFFu) * 64 + j]);
    acc += h0 * w0 + h1 * w1 + h2 * w2 + h3 * w3;
    wsum += w0 + w1 + w2 + w3;
  }
  for (; i < d; ++i) {
    uint2 c = csr[start + i];
    float w = decw<LI>(c);
    acc += bf2f(hbin[(c.x & 0x1FFFFu) * 64 + j]) * w;
    wsum += w;
  }
  agg[n * 64 + j] = acc / fmaxf(wsum, 1e-12f);
}

// ---------- 4. node MLP + residual + LayerNorm ----------
__global__ __launch_bounds__(256, 2) void k_mlp(const float* __restrict__ nw,
                                                const float* __restrict__ nb,
                                                const float* __restrict__ g,
                                                const float* __restrict__ b,
                                                const float* __restrict__ hin,
                                                const float* __restrict__ agg,
                                                float* __restrict__ hout,
                                                unsigned short* __restrict__ hbout) {
  int j = threadIdx.x & 63;
  int gw = (blockIdx.x * 256 + threadIdx.x) >> 6;  // global wave id
  float wreg[128];
#pragma unroll
  for (int k = 0; k < 128; k++) wreg[k] = nw[k * 64 + j];  // lane j = output col j
  float nbj = nb[j], gj = g[j], bj = b[j];
  int n0 = gw * NPW;
  for (int n = n0; n < n0 + NPW; ++n) {
    if (n >= N_NODES) break;
    float hv = hin[n * 64 + j];
    float av = agg[n * 64 + j];
    float acc = nbj;
#pragma unroll
    for (int k = 0; k < 64; k++) acc += bcast(hv, k) * wreg[k];
#pragma unroll
    for (int k = 0; k < 64; k++) acc += bcast(av, k) * wreg[64 + k];
    float r = hv + fmaxf(acc, 0.f);
    float s = r;
#pragma unroll
    for (int off = 32; off; off >>= 1) s += __shfl_xor(s, off);
    float mu = s * (1.f / 64.f);
    float dd = r - mu;
    float v2 = dd * dd;
#pragma unroll
    for (int off = 32; off; off >>= 1) v2 += __shfl_xor(v2, off);
    float rs = rsqrtf(v2 * (1.f / 64.f) + 1e-5f);
    float o = dd * rs * gj + bj;
    hout[n * 64 + j] = o;
    hbout[n * 64 + j] = f2bf(o);
  }
}

// ---------- 5. head: out = relu(h@hw1+hb1)@hw2 + hb2 ----------
__global__ __launch_bounds__(256, 2) void k_head(const float* __restrict__ hw1,
                                                 const float* __restrict__ hb1,
                                                 const float* __restrict__ hw2,
                                                 const float* __restrict__ hb2,
                                                 const float* __restrict__ hin,
                                                 float* __restrict__ out) {
  int j = threadIdx.x & 63;
  int jj = j & 31;
  int gw = (blockIdx.x * 256 + threadIdx.x) >> 6;
  float w1[64];
#pragma unroll
  for (int k = 0; k < 64; k++) w1[k] = hw1[k * 32 + jj];
  float hb1j = hb1[jj];
  float hw2j = hw2[jj];
  float hb2v = hb2[0];
  int n0 = gw * NPW;
  for (int n = n0; n < n0 + NPW; ++n) {
    if (n >= N_NODES) break;
    float hv = hin[n * 64 + j];
    float acc = hb1j;
#pragma unroll
    for (int k = 0; k < 64; k++) acc += bcast(hv, k) * w1[k];
    float z = fmaxf(acc, 0.f) * hw2j;
    if (j >= 32) z = 0.f;  // upper 32 lanes duplicate lower-half columns
#pragma unroll
    for (int off = 32; off; off >>= 1) z += __shfl_xor(z, off);
    if (j == 0) out[n] = z + hb2v;
  }
}

// ---------- launch ----------
static inline size_t align256(size_t x) { return (x + 255) & ~size_t(255); }

extern "C" void kernel_launch(void* const* d_in, const int* in_sizes, int n_in,
                              void* d_out, int out_size, void* d_ws, size_t ws_size,
                              hipStream_t stream) {
  const float* x   = (const float*)d_in[0];
  const int*   ei  = (const int*)d_in[1];
  const float* ea  = (const float*)d_in[2];
  const float* Wp  = (const float*)d_in[3];
  const float* bp  = (const float*)d_in[4];
  const float* ew1 = (const float*)d_in[5];
  const float* eb1 = (const float*)d_in[6];
  const float* ew2 = (const float*)d_in[7];
  const float* eb2 = (const float*)d_in[8];
  const float* nw  = (const float*)d_in[9];
  const float* nb  = (const float*)d_in[10];
  const float* lng = (const float*)d_in[11];
  const float* lnb = (const float*)d_in[12];
  const float* hw1 = (const float*)d_in[13];
  const float* hb1 = (const float*)d_in[14];
  const float* hw2 = (const float*)d_in[15];
  const float* hb2 = (const float*)d_in[16];
  float* out = (float*)d_out;

  char* ws = (char*)d_ws;
  size_t off = 0;
  float* h0f = (float*)(ws + off); off = align256(off + (size_t)N_NODES * 64 * 4);
  float* h1f = (float*)(ws + off); off = align256(off + (size_t)N_NODES * 64 * 4);
  float* agg = (float*)(ws + off); off = align256(off + (size_t)N_NODES * 64 * 4);
  unsigned short* hb0 = (unsigned short*)(ws + off); off = align256(off + (size_t)N_NODES * 64 * 2);
  unsigned short* hb1b = (unsigned short*)(ws + off); off = align256(off + (size_t)N_NODES * 64 * 2);
  uint2* csr = (uint2*)(ws + off); off = align256(off + (size_t)N_EDGES * 8);
  int* deg    = (int*)(ws + off); off = align256(off + (size_t)N_NODES * 4);
  int* offs   = (int*)(ws + off); off = align256(off + (size_t)N_NODES * 4);
  int* cursor = (int*)(ws + off); off = align256(off + (size_t)N_NODES * 4);
  int* bsums  = (int*)(ws + off); off = align256(off + 1024);

  const int NB_SCAN = (N_NODES + 255) / 256;  // 196

  hipMemsetAsync(deg, 0, (size_t)N_NODES * 4, stream);

  k_proj<<<(N_NODES * 64 + 255) / 256, 256, 0, stream>>>(x, Wp, bp, h0f, hb0);
  k_hist<<<(N_EDGES + 255) / 256, 256, 0, stream>>>(ei, deg);
  k_scan1<<<NB_SCAN, 256, 0, stream>>>(deg, offs, bsums);
  k_scan2<<<1, 256, 0, stream>>>(bsums, NB_SCAN);
  k_scan3<<<NB_SCAN, 256, 0, stream>>>(offs, bsums, cursor);
  k_fill<<<(N_EDGES + 255) / 256, 256, 0, stream>>>(ei, ea, ew1, eb1, ew2, eb2, cursor, csr);

  const int aggGrid = (N_NODES * 64 + 255) / 256;           // wave per node
  const int mlpGrid = ((N_NODES + NPW - 1) / NPW + 3) / 4;  // 4 waves/block

  // layer 0: h0 -> h1
  k_agg<0><<<aggGrid, 256, 0, stream>>>(csr, offs, deg, hb0, agg);
  k_mlp<<<mlpGrid, 256, 0, stream>>>(nw + 0 * 8192, nb + 0 * 64, lng + 0 * 64, lnb + 0 * 64,
                                     h0f, agg, h1f, hb1b);
  // layer 1: h1 -> h0
  k_agg<1><<<aggGrid, 256, 0, stream>>>(csr, offs, deg, hb1b, agg);
  k_mlp<<<mlpGrid, 256, 0, stream>>>(nw + 1 * 8192, nb + 1 * 64, lng + 1 * 64, lnb + 1 * 64,
                                     h1f, agg, h0f, hb0);
  // layer 2: h0 -> h1
  k_agg<2><<<aggGrid, 256, 0, stream>>>(csr, offs, deg, hb0, agg);
  k_mlp<<<mlpGrid, 256, 0, stream>>>(nw + 2 * 8192, nb + 2 * 64, lng + 2 * 64, lnb + 2 * 64,
                                     h0f, agg, h1f, hb1b);

  k_head<<<mlpGrid, 256, 0, stream>>>(hw1, hb1, hw2, hb2, h1f, out);
}

// Round 4
// 348.415 us; speedup vs baseline: 1.8521x; 1.3113x over previous
//
#include <hip/hip_runtime.h>
#include <math.h>

#define N_NODES 50000
#define N_EDGES 800000
#define NPW 16        // nodes per wave in head kernel
#define N_STRIPS 3125 // 50000 / 16

typedef __attribute__((ext_vector_type(8))) short bf16x8;
typedef __attribute__((ext_vector_type(4))) float f32x4;

// ---------- helpers ----------
__device__ __forceinline__ float bcast(float v, int lane) {
  return __int_as_float(__builtin_amdgcn_readlane(__float_as_int(v), lane));
}
__device__ __forceinline__ unsigned short f2bf(float f) {  // RNE f32->bf16
  unsigned int u = __float_as_uint(f);
  u += 0x7FFFu + ((u >> 16) & 1u);
  return (unsigned short)(u >> 16);
}
__device__ __forceinline__ float bf2f(unsigned short s) {
  return __uint_as_float(((unsigned int)s) << 16);
}

// ---------- 1. input projection: h = relu(x @ Wp + bp); writes f32 + bf16 ----------
__global__ __launch_bounds__(256) void k_proj(const float* __restrict__ x,
                                              const float* __restrict__ Wp,
                                              const float* __restrict__ bp,
                                              float* __restrict__ h,
                                              unsigned short* __restrict__ hb) {
  int idx = blockIdx.x * 256 + threadIdx.x;
  int n = idx >> 6, j = idx & 63;
  if (n >= N_NODES) return;
  float acc = bp[j];
#pragma unroll
  for (int k = 0; k < 10; k++) acc += x[n * 10 + k] * Wp[k * 64 + j];
  float r = fmaxf(acc, 0.f);
  h[n * 64 + j] = r;
  hb[n * 64 + j] = f2bf(r);
}

// ---------- 2. CSR build ----------
__global__ __launch_bounds__(256) void k_hist(const int* __restrict__ ei, int* __restrict__ deg) {
  int e = blockIdx.x * 256 + threadIdx.x;
  if (e >= N_EDGES) return;
  atomicAdd(&deg[ei[N_EDGES + e]], 1);
}

__global__ __launch_bounds__(256) void k_scan1(const int* __restrict__ deg,
                                               int* __restrict__ offs,
                                               int* __restrict__ bsums) {
  __shared__ int sm[256];
  int i = blockIdx.x * 256 + threadIdx.x;
  int v = (i < N_NODES) ? deg[i] : 0;
  sm[threadIdx.x] = v;
  __syncthreads();
#pragma unroll
  for (int off = 1; off < 256; off <<= 1) {
    int t = (threadIdx.x >= off) ? sm[threadIdx.x - off] : 0;
    __syncthreads();
    sm[threadIdx.x] += t;
    __syncthreads();
  }
  if (i < N_NODES) offs[i] = sm[threadIdx.x] - v;  // exclusive
  if (threadIdx.x == 255) bsums[blockIdx.x] = sm[255];
}

__global__ __launch_bounds__(256) void k_scan2(int* __restrict__ bsums, int nb) {
  __shared__ int sm[256];
  int t = threadIdx.x;
  int v = (t < nb) ? bsums[t] : 0;
  sm[t] = v;
  __syncthreads();
#pragma unroll
  for (int off = 1; off < 256; off <<= 1) {
    int u = (t >= off) ? sm[t - off] : 0;
    __syncthreads();
    sm[t] += u;
    __syncthreads();
  }
  if (t < nb) bsums[t] = sm[t] - v;  // exclusive
}

__global__ __launch_bounds__(256) void k_scan3(int* __restrict__ offs,
                                               const int* __restrict__ bsums,
                                               int* __restrict__ cursor) {
  int i = blockIdx.x * 256 + threadIdx.x;
  if (i >= N_NODES) return;
  int o = offs[i] + bsums[blockIdx.x];
  offs[i] = o;
  cursor[i] = o;
}

// fill CSR; fuse the 3-layer edge MLP. 8B record:
//   x = src(17 bits) | q0<<17 ; y = q1 | q2<<15   (q = round(w*32767), 15-bit)
__global__ __launch_bounds__(256) void k_fill(const int* __restrict__ ei,
                                              const float* __restrict__ ea,
                                              const float* __restrict__ ew1,
                                              const float* __restrict__ eb1,
                                              const float* __restrict__ ew2,
                                              const float* __restrict__ eb2,
                                              int* __restrict__ cursor,
                                              uint2* __restrict__ csr) {
  int e = blockIdx.x * 256 + threadIdx.x;
  if (e >= N_EDGES) return;
  int s = ei[e];
  int d = ei[N_EDGES + e];
  float a0 = ea[e * 3 + 0], a1 = ea[e * 3 + 1], a2 = ea[e * 3 + 2];
  int q[3];
#pragma unroll
  for (int l = 0; l < 3; l++) {
    float z = eb2[l];
#pragma unroll
    for (int t = 0; t < 16; t++) {
      float hd = a0 * ew1[l * 48 + t] + a1 * ew1[l * 48 + 16 + t] +
                 a2 * ew1[l * 48 + 32 + t] + eb1[l * 16 + t];
      z += fmaxf(hd, 0.f) * ew2[l * 16 + t];
    }
    float w = 1.f / (1.f + __expf(-z));
    q[l] = __float2int_rn(w * 32767.f);
  }
  unsigned int w0 = (unsigned int)s | ((unsigned int)q[0] << 17);
  unsigned int w1 = (unsigned int)q[1] | ((unsigned int)q[2] << 15);
  int p = atomicAdd(&cursor[d], 1);
  csr[p] = make_uint2(w0, w1);
}

template <int LI>
__device__ __forceinline__ float decw(uint2 c) {
  unsigned int q = (LI == 0) ? (c.x >> 17) : (LI == 1) ? (c.y & 0x7FFFu) : (c.y >> 15);
  return (float)q * (1.f / 32767.f);
}

// ---------- 3. aggregation: wave per node, lane = feature, bf16 gather, bf16 out ----------
template <int LI>
__global__ __launch_bounds__(256, 4) void k_agg(const uint2* __restrict__ csr,
                                                const int* __restrict__ offs,
                                                const int* __restrict__ deg,
                                                const unsigned short* __restrict__ hbin,
                                                unsigned short* __restrict__ ab) {
  int n = (blockIdx.x * 256 + threadIdx.x) >> 6;
  int j = threadIdx.x & 63;
  if (n >= N_NODES) return;
  int start = offs[n];
  int d = deg[n];
  float acc = 0.f, wsum = 0.f;
  int i = 0;
  for (; i + 4 <= d; i += 4) {
    uint2 c0 = csr[start + i + 0];
    uint2 c1 = csr[start + i + 1];
    uint2 c2 = csr[start + i + 2];
    uint2 c3 = csr[start + i + 3];
    float w0 = decw<LI>(c0), w1 = decw<LI>(c1), w2 = decw<LI>(c2), w3 = decw<LI>(c3);
    float h0 = bf2f(hbin[(c0.x & 0x1FFFFu) * 64 + j]);
    float h1 = bf2f(hbin[(c1.x & 0x1FFFFu) * 64 + j]);
    float h2 = bf2f(hbin[(c2.x & 0x1FFFFu) * 64 + j]);
    float h3 = bf2f(hbin[(c3.x & 0x1FFFFu) * 64 + j]);
    acc += h0 * w0 + h1 * w1 + h2 * w2 + h3 * w3;
    wsum += w0 + w1 + w2 + w3;
  }
  for (; i < d; ++i) {
    uint2 c = csr[start + i];
    float w = decw<LI>(c);
    acc += bf2f(hbin[(c.x & 0x1FFFFu) * 64 + j]) * w;
    wsum += w;
  }
  ab[n * 64 + j] = f2bf(acc / fmaxf(wsum, 1e-12f));
}

// ---------- 4. node MLP (MFMA) + residual + LayerNorm ----------
// C(50000x64) = [hb | ab](50000x128, bf16) @ nw(128x64, cast bf16)
// wave strip = 16 nodes x 64 cols; 4 col-tiles x 4 k-chunks of mfma 16x16x32_bf16
// C/D layout: col=lane&15, row=(lane>>4)*4+reg  [verified, learn_hip m89/m91]
// A layout:   m=lane&15,  k=(lane>>4)*8+j       [learn_hip m120]
// B layout:   n=lane&15,  k=(lane>>4)*8+j
__global__ __launch_bounds__(256) void k_mlp(const float* __restrict__ nw,
                                             const float* __restrict__ nb,
                                             const float* __restrict__ g,
                                             const float* __restrict__ b,
                                             const float* __restrict__ hin,
                                             const unsigned short* __restrict__ hb_in,
                                             const unsigned short* __restrict__ ab_in,
                                             float* __restrict__ hout,
                                             unsigned short* __restrict__ hbout) {
  int lane = threadIdx.x & 63;
  int n16 = lane & 15;   // col within tile (C); row within A
  int q = lane >> 4;     // quad
  int wid = (blockIdx.x * 256 + threadIdx.x) >> 6;
  int nwaves = gridDim.x * 4;

  // B fragments, once per wave (nw is L2-hot, 32KB)
  bf16x8 bfr[4][4];
#pragma unroll
  for (int t = 0; t < 4; t++)
#pragma unroll
    for (int kc = 0; kc < 4; kc++) {
      bf16x8 v;
#pragma unroll
      for (int jj = 0; jj < 8; jj++) {
        int k = kc * 32 + q * 8 + jj;
        v[jj] = (short)f2bf(nw[k * 64 + t * 16 + n16]);
      }
      bfr[t][kc] = v;
    }
  float nbv[4], gv[4], bv[4];
#pragma unroll
  for (int t = 0; t < 4; t++) {
    nbv[t] = nb[t * 16 + n16];
    gv[t] = g[t * 16 + n16];
    bv[t] = b[t * 16 + n16];
  }

  for (int s = wid; s < N_STRIPS; s += nwaves) {
    int n0 = s * 16;
    f32x4 acc[4] = {{0.f, 0.f, 0.f, 0.f}, {0.f, 0.f, 0.f, 0.f},
                    {0.f, 0.f, 0.f, 0.f}, {0.f, 0.f, 0.f, 0.f}};
#pragma unroll
    for (int kc = 0; kc < 4; kc++) {
      const unsigned short* base = (kc < 2) ? hb_in : ab_in;
      bf16x8 a = *(const bf16x8*)(base + (size_t)(n0 + n16) * 64 + (kc & 1) * 32 + q * 8);
#pragma unroll
      for (int t = 0; t < 4; t++)
        acc[t] = __builtin_amdgcn_mfma_f32_16x16x32_bf16(a, bfr[t][kc], acc[t], 0, 0, 0);
    }
    // epilogue: r = hin + relu(acc + nb); LayerNorm over 64 cols per row
    float r[4][4];           // [t][reg]
    float p[4], p2[4];       // per-reg row sums (partial over this lane's 4 cols)
#pragma unroll
    for (int rg = 0; rg < 4; rg++) { p[rg] = 0.f; p2[rg] = 0.f; }
#pragma unroll
    for (int t = 0; t < 4; t++)
#pragma unroll
      for (int rg = 0; rg < 4; rg++) {
        int row = n0 + q * 4 + rg;
        float hv = hin[row * 64 + t * 16 + n16];
        float rr = hv + fmaxf(acc[t][rg] + nbv[t], 0.f);
        r[t][rg] = rr;
        p[rg] += rr;
        p2[rg] += rr * rr;
      }
#pragma unroll
    for (int rg = 0; rg < 4; rg++)
#pragma unroll
      for (int off = 1; off < 16; off <<= 1) {
        p[rg] += __shfl_xor(p[rg], off);
        p2[rg] += __shfl_xor(p2[rg], off);
      }
#pragma unroll
    for (int rg = 0; rg < 4; rg++) {
      float mu = p[rg] * (1.f / 64.f);
      float var = p2[rg] * (1.f / 64.f) - mu * mu;
      float rs = rsqrtf(fmaxf(var, 0.f) + 1e-5f);
      int row = n0 + q * 4 + rg;
#pragma unroll
      for (int t = 0; t < 4; t++) {
        float o = (r[t][rg] - mu) * rs * gv[t] + bv[t];
        hout[row * 64 + t * 16 + n16] = o;
        hbout[row * 64 + t * 16 + n16] = f2bf(o);
      }
    }
  }
}

// ---------- 5. head: out = relu(h@hw1+hb1)@hw2 + hb2 ----------
__global__ __launch_bounds__(256, 2) void k_head(const float* __restrict__ hw1,
                                                 const float* __restrict__ hb1,
                                                 const float* __restrict__ hw2,
                                                 const float* __restrict__ hb2,
                                                 const float* __restrict__ hin,
                                                 float* __restrict__ out) {
  int j = threadIdx.x & 63;
  int jj = j & 31;
  int gw = (blockIdx.x * 256 + threadIdx.x) >> 6;
  float w1[64];
#pragma unroll
  for (int k = 0; k < 64; k++) w1[k] = hw1[k * 32 + jj];
  float hb1j = hb1[jj];
  float hw2j = hw2[jj];
  float hb2v = hb2[0];
  int n0 = gw * NPW;
  for (int n = n0; n < n0 + NPW; ++n) {
    if (n >= N_NODES) break;
    float hv = hin[n * 64 + j];
    float acc = hb1j;
#pragma unroll
    for (int k = 0; k < 64; k++) acc += bcast(hv, k) * w1[k];
    float z = fmaxf(acc, 0.f) * hw2j;
    if (j >= 32) z = 0.f;  // upper 32 lanes duplicate lower-half columns
#pragma unroll
    for (int off = 32; off; off >>= 1) z += __shfl_xor(z, off);
    if (j == 0) out[n] = z + hb2v;
  }
}

// ---------- launch ----------
static inline size_t align256(size_t x) { return (x + 255) & ~size_t(255); }

extern "C" void kernel_launch(void* const* d_in, const int* in_sizes, int n_in,
                              void* d_out, int out_size, void* d_ws, size_t ws_size,
                              hipStream_t stream) {
  const float* x   = (const float*)d_in[0];
  const int*   ei  = (const int*)d_in[1];
  const float* ea  = (const float*)d_in[2];
  const float* Wp  = (const float*)d_in[3];
  const float* bp  = (const float*)d_in[4];
  const float* ew1 = (const float*)d_in[5];
  const float* eb1 = (const float*)d_in[6];
  const float* ew2 = (const float*)d_in[7];
  const float* eb2 = (const float*)d_in[8];
  const float* nw  = (const float*)d_in[9];
  const float* nb  = (const float*)d_in[10];
  const float* lng = (const float*)d_in[11];
  const float* lnb = (const float*)d_in[12];
  const float* hw1 = (const float*)d_in[13];
  const float* hb1 = (const float*)d_in[14];
  const float* hw2 = (const float*)d_in[15];
  const float* hb2 = (const float*)d_in[16];
  float* out = (float*)d_out;

  char* ws = (char*)d_ws;
  size_t off = 0;
  float* h0f = (float*)(ws + off); off = align256(off + (size_t)N_NODES * 64 * 4);
  float* h1f = (float*)(ws + off); off = align256(off + (size_t)N_NODES * 64 * 4);
  unsigned short* hb0  = (unsigned short*)(ws + off); off = align256(off + (size_t)N_NODES * 64 * 2);
  unsigned short* hb1b = (unsigned short*)(ws + off); off = align256(off + (size_t)N_NODES * 64 * 2);
  unsigned short* ab   = (unsigned short*)(ws + off); off = align256(off + (size_t)N_NODES * 64 * 2);
  uint2* csr = (uint2*)(ws + off); off = align256(off + (size_t)N_EDGES * 8);
  int* deg    = (int*)(ws + off); off = align256(off + (size_t)N_NODES * 4);
  int* offs   = (int*)(ws + off); off = align256(off + (size_t)N_NODES * 4);
  int* cursor = (int*)(ws + off); off = align256(off + (size_t)N_NODES * 4);
  int* bsums  = (int*)(ws + off); off = align256(off + 1024);

  const int NB_SCAN = (N_NODES + 255) / 256;  // 196

  hipMemsetAsync(deg, 0, (size_t)N_NODES * 4, stream);

  k_proj<<<(N_NODES * 64 + 255) / 256, 256, 0, stream>>>(x, Wp, bp, h0f, hb0);
  k_hist<<<(N_EDGES + 255) / 256, 256, 0, stream>>>(ei, deg);
  k_scan1<<<NB_SCAN, 256, 0, stream>>>(deg, offs, bsums);
  k_scan2<<<1, 256, 0, stream>>>(bsums, NB_SCAN);
  k_scan3<<<NB_SCAN, 256, 0, stream>>>(offs, bsums, cursor);
  k_fill<<<(N_EDGES + 255) / 256, 256, 0, stream>>>(ei, ea, ew1, eb1, ew2, eb2, cursor, csr);

  const int aggGrid = (N_NODES * 64 + 255) / 256;           // wave per node
  const int mlpGrid = 392;                                  // 1568 waves, ~2 strips each
  const int headGrid = ((N_NODES + NPW - 1) / NPW + 3) / 4;

  // layer 0: h0 -> h1
  k_agg<0><<<aggGrid, 256, 0, stream>>>(csr, offs, deg, hb0, ab);
  k_mlp<<<mlpGrid, 256, 0, stream>>>(nw + 0 * 8192, nb + 0 * 64, lng + 0 * 64, lnb + 0 * 64,
                                     h0f, hb0, ab, h1f, hb1b);
  // layer 1: h1 -> h0
  k_agg<1><<<aggGrid, 256, 0, stream>>>(csr, offs, deg, hb1b, ab);
  k_mlp<<<mlpGrid, 256, 0, stream>>>(nw + 1 * 8192, nb + 1 * 64, lng + 1 * 64, lnb + 1 * 64,
                                     h1f, hb1b, ab, h0f, hb0);
  // layer 2: h0 -> h1
  k_agg<2><<<aggGrid, 256, 0, stream>>>(csr, offs, deg, hb0, ab);
  k_mlp<<<mlpGrid, 256, 0, stream>>>(nw + 2 * 8192, nb + 2 * 64, lng + 2 * 64, lnb + 2 * 64,
                                     h0f, hb0, ab, h1f, hb1b);

  k_head<<<headGrid, 256, 0, stream>>>(hw1, hb1, hw2, hb2, h1f, out);
}

// Round 5
// 319.280 us; speedup vs baseline: 2.0211x; 1.0913x over previous
//
#include <hip/hip_runtime.h>
#include <math.h>

#define N_NODES 50000
#define N_EDGES 800000
#define NPW 16          // nodes per wave in head kernel
#define N_STRIPS 3125   // 50000 / 16
#define PART_SZ 6250    // N_NODES / 8 (dst partition per XCD)
#define FILL_CHUNK 2048 // edges per k_fill block

typedef __attribute__((ext_vector_type(8))) short bf16x8;
typedef __attribute__((ext_vector_type(4))) float f32x4;

// ---------- helpers ----------
__device__ __forceinline__ float bcast(float v, int lane) {
  return __int_as_float(__builtin_amdgcn_readlane(__float_as_int(v), lane));
}
__device__ __forceinline__ unsigned short f2bf(float f) {  // RNE f32->bf16
  unsigned int u = __float_as_uint(f);
  u += 0x7FFFu + ((u >> 16) & 1u);
  return (unsigned short)(u >> 16);
}
__device__ __forceinline__ float bf2f(unsigned short s) {
  return __uint_as_float(((unsigned int)s) << 16);
}
__device__ __forceinline__ float bfLO(unsigned int u) {  // low bf16 of packed pair
  return __uint_as_float(u << 16);
}
__device__ __forceinline__ float bfHI(unsigned int u) {  // high bf16 of packed pair
  return __uint_as_float(u & 0xFFFF0000u);
}

// ---------- 1. input projection: h = relu(x @ Wp + bp); writes f32 + bf16 ----------
__global__ __launch_bounds__(256) void k_proj(const float* __restrict__ x,
                                              const float* __restrict__ Wp,
                                              const float* __restrict__ bp,
                                              float* __restrict__ h,
                                              unsigned short* __restrict__ hb) {
  int idx = blockIdx.x * 256 + threadIdx.x;
  int n = idx >> 6, j = idx & 63;
  if (n >= N_NODES) return;
  float acc = bp[j];
#pragma unroll
  for (int k = 0; k < 10; k++) acc += x[n * 10 + k] * Wp[k * 64 + j];
  float r = fmaxf(acc, 0.f);
  h[n * 64 + j] = r;
  hb[n * 64 + j] = f2bf(r);
}

// ---------- 2. CSR build ----------
__global__ __launch_bounds__(256) void k_hist(const int* __restrict__ ei, int* __restrict__ deg) {
  int e = blockIdx.x * 256 + threadIdx.x;
  if (e >= N_EDGES) return;
  atomicAdd(&deg[ei[N_EDGES + e]], 1);
}

__global__ __launch_bounds__(256) void k_scan1(const int* __restrict__ deg,
                                               int* __restrict__ offs,
                                               int* __restrict__ bsums) {
  __shared__ int sm[256];
  int i = blockIdx.x * 256 + threadIdx.x;
  int v = (i < N_NODES) ? deg[i] : 0;
  sm[threadIdx.x] = v;
  __syncthreads();
#pragma unroll
  for (int off = 1; off < 256; off <<= 1) {
    int t = (threadIdx.x >= off) ? sm[threadIdx.x - off] : 0;
    __syncthreads();
    sm[threadIdx.x] += t;
    __syncthreads();
  }
  if (i < N_NODES) offs[i] = sm[threadIdx.x] - v;  // exclusive
  if (threadIdx.x == 255) bsums[blockIdx.x] = sm[255];
}

__global__ __launch_bounds__(256) void k_scan2(int* __restrict__ bsums, int nb) {
  __shared__ int sm[256];
  int t = threadIdx.x;
  int v = (t < nb) ? bsums[t] : 0;
  sm[t] = v;
  __syncthreads();
#pragma unroll
  for (int off = 1; off < 256; off <<= 1) {
    int u = (t >= off) ? sm[t - off] : 0;
    __syncthreads();
    sm[t] += u;
    __syncthreads();
  }
  if (t < nb) bsums[t] = sm[t] - v;  // exclusive
}

__global__ __launch_bounds__(256) void k_scan3(int* __restrict__ offs,
                                               const int* __restrict__ bsums,
                                               int* __restrict__ cursor) {
  int i = blockIdx.x * 256 + threadIdx.x;
  if (i >= N_NODES) return;
  int o = offs[i] + bsums[blockIdx.x];
  offs[i] = o;
  cursor[i] = o;
}

// fill CSR, XCD-partitioned by dst range so scattered writes stay in one XCD's L2
// and merge before writeback (R4 counter: WRITE_SIZE = 800k x 64B line churn).
// 8B record: x = src(17b) | q0<<17 ; y = q1 | q2<<15  (q = round(w*32767))
__global__ __launch_bounds__(256) void k_fill(const int* __restrict__ ei,
                                              const float* __restrict__ ea,
                                              const float* __restrict__ ew1,
                                              const float* __restrict__ eb1,
                                              const float* __restrict__ ew2,
                                              const float* __restrict__ eb2,
                                              int* __restrict__ cursor,
                                              uint2* __restrict__ csr) {
  int p = blockIdx.x & 7;          // dst partition (blockIdx%8 ~ XCD, heuristic)
  int base = (blockIdx.x >> 3) * FILL_CHUNK;
  __shared__ int qcnt;
  __shared__ int q[FILL_CHUNK];
  if (threadIdx.x == 0) qcnt = 0;
  __syncthreads();
#pragma unroll
  for (int r = 0; r < FILL_CHUNK / 256; r++) {
    int e = base + r * 256 + threadIdx.x;
    if (e < N_EDGES) {
      int d = ei[N_EDGES + e];
      if (d / PART_SZ == p) {
        int pos = atomicAdd(&qcnt, 1);
        q[pos] = e;
      }
    }
  }
  __syncthreads();
  int m = qcnt;
  for (int i = threadIdx.x; i < m; i += 256) {
    int e = q[i];
    int s = ei[e];
    int d = ei[N_EDGES + e];
    float a0 = ea[e * 3 + 0], a1 = ea[e * 3 + 1], a2 = ea[e * 3 + 2];
    int qq[3];
#pragma unroll
    for (int l = 0; l < 3; l++) {
      float z = eb2[l];
#pragma unroll
      for (int t = 0; t < 16; t++) {
        float hd = a0 * ew1[l * 48 + t] + a1 * ew1[l * 48 + 16 + t] +
                   a2 * ew1[l * 48 + 32 + t] + eb1[l * 16 + t];
        z += fmaxf(hd, 0.f) * ew2[l * 16 + t];
      }
      float w = 1.f / (1.f + __expf(-z));
      qq[l] = __float2int_rn(w * 32767.f);
    }
    unsigned int w0 = (unsigned int)s | ((unsigned int)qq[0] << 17);
    unsigned int w1 = (unsigned int)qq[1] | ((unsigned int)qq[2] << 15);
    int pos = atomicAdd(&cursor[d], 1);
    csr[pos] = make_uint2(w0, w1);
  }
}

template <int LI>
__device__ __forceinline__ float decw(uint2 c) {
  unsigned int q = (LI == 0) ? (c.x >> 17) : (LI == 1) ? (c.y & 0x7FFFu) : (c.y >> 15);
  return (float)q * (1.f / 32767.f);
}

// ---------- 3. aggregation: 4 nodes/wave (16 lanes/node, 4 feats/lane) ----------
// 16 outstanding dwordx2 gathers per unrolled iteration -> 4x the MLP of R4.
template <int LI>
__global__ __launch_bounds__(256, 8) void k_agg(const uint2* __restrict__ csr,
                                                const int* __restrict__ offs,
                                                const int* __restrict__ deg,
                                                const unsigned short* __restrict__ hbin,
                                                unsigned short* __restrict__ ab) {
  int lane = threadIdx.x & 63;
  int sub = lane >> 4;   // node slot within wave
  int jj = lane & 15;    // feature group: features [4jj, 4jj+4)
  int gw = (blockIdx.x * 256 + threadIdx.x) >> 6;
  int n = gw * 4 + sub;
  bool active = n < N_NODES;
  int start = active ? offs[n] : 0;
  int d = active ? deg[n] : 0;
  const uint2* hrow = (const uint2*)hbin;  // row n at hrow[n*16 + jj]
  float a0 = 0.f, a1 = 0.f, a2 = 0.f, a3 = 0.f, ws = 0.f;
  int i = 0;
  for (; i + 4 <= d; i += 4) {
    uint2 c0 = csr[start + i + 0];
    uint2 c1 = csr[start + i + 1];
    uint2 c2 = csr[start + i + 2];
    uint2 c3 = csr[start + i + 3];
    uint2 g0 = hrow[(c0.x & 0x1FFFFu) * 16 + jj];
    uint2 g1 = hrow[(c1.x & 0x1FFFFu) * 16 + jj];
    uint2 g2 = hrow[(c2.x & 0x1FFFFu) * 16 + jj];
    uint2 g3 = hrow[(c3.x & 0x1FFFFu) * 16 + jj];
    float w0 = decw<LI>(c0), w1 = decw<LI>(c1), w2 = decw<LI>(c2), w3 = decw<LI>(c3);
    a0 += bfLO(g0.x) * w0 + bfLO(g1.x) * w1 + bfLO(g2.x) * w2 + bfLO(g3.x) * w3;
    a1 += bfHI(g0.x) * w0 + bfHI(g1.x) * w1 + bfHI(g2.x) * w2 + bfHI(g3.x) * w3;
    a2 += bfLO(g0.y) * w0 + bfLO(g1.y) * w1 + bfLO(g2.y) * w2 + bfLO(g3.y) * w3;
    a3 += bfHI(g0.y) * w0 + bfHI(g1.y) * w1 + bfHI(g2.y) * w2 + bfHI(g3.y) * w3;
    ws += w0 + w1 + w2 + w3;
  }
  for (; i < d; ++i) {
    uint2 c = csr[start + i];
    uint2 g = hrow[(c.x & 0x1FFFFu) * 16 + jj];
    float w = decw<LI>(c);
    a0 += bfLO(g.x) * w;
    a1 += bfHI(g.x) * w;
    a2 += bfLO(g.y) * w;
    a3 += bfHI(g.y) * w;
    ws += w;
  }
  if (active) {
    float inv = fmaxf(ws, 1e-12f);
    a0 /= inv; a1 /= inv; a2 /= inv; a3 /= inv;
    unsigned int u0 = (unsigned int)f2bf(a0) | ((unsigned int)f2bf(a1) << 16);
    unsigned int u1 = (unsigned int)f2bf(a2) | ((unsigned int)f2bf(a3) << 16);
    ((uint2*)ab)[n * 16 + jj] = make_uint2(u0, u1);
  }
}

// ---------- 4. node MLP (MFMA) + residual + LayerNorm ----------
// C(50000x64) = [hb | ab](50000x128, bf16) @ nw(128x64, cast bf16)
// C/D layout: col=lane&15, row=(lane>>4)*4+reg ; A/B: k=(lane>>4)*8+j
__global__ __launch_bounds__(256) void k_mlp(const float* __restrict__ nw,
                                             const float* __restrict__ nb,
                                             const float* __restrict__ g,
                                             const float* __restrict__ b,
                                             const float* __restrict__ hin,
                                             const unsigned short* __restrict__ hb_in,
                                             const unsigned short* __restrict__ ab_in,
                                             float* __restrict__ hout,
                                             unsigned short* __restrict__ hbout) {
  int lane = threadIdx.x & 63;
  int n16 = lane & 15;
  int q = lane >> 4;
  int wid = (blockIdx.x * 256 + threadIdx.x) >> 6;
  int nwaves = gridDim.x * 4;

  bf16x8 bfr[4][4];
#pragma unroll
  for (int t = 0; t < 4; t++)
#pragma unroll
    for (int kc = 0; kc < 4; kc++) {
      bf16x8 v;
#pragma unroll
      for (int jj = 0; jj < 8; jj++) {
        int k = kc * 32 + q * 8 + jj;
        v[jj] = (short)f2bf(nw[k * 64 + t * 16 + n16]);
      }
      bfr[t][kc] = v;
    }
  float nbv[4], gv[4], bv[4];
#pragma unroll
  for (int t = 0; t < 4; t++) {
    nbv[t] = nb[t * 16 + n16];
    gv[t] = g[t * 16 + n16];
    bv[t] = b[t * 16 + n16];
  }

  for (int s = wid; s < N_STRIPS; s += nwaves) {
    int n0 = s * 16;
    f32x4 acc[4] = {{0.f, 0.f, 0.f, 0.f}, {0.f, 0.f, 0.f, 0.f},
                    {0.f, 0.f, 0.f, 0.f}, {0.f, 0.f, 0.f, 0.f}};
#pragma unroll
    for (int kc = 0; kc < 4; kc++) {
      const unsigned short* base = (kc < 2) ? hb_in : ab_in;
      bf16x8 a = *(const bf16x8*)(base + (size_t)(n0 + n16) * 64 + (kc & 1) * 32 + q * 8);
#pragma unroll
      for (int t = 0; t < 4; t++)
        acc[t] = __builtin_amdgcn_mfma_f32_16x16x32_bf16(a, bfr[t][kc], acc[t], 0, 0, 0);
    }
    float r[4][4];
    float p[4], p2[4];
#pragma unroll
    for (int rg = 0; rg < 4; rg++) { p[rg] = 0.f; p2[rg] = 0.f; }
#pragma unroll
    for (int t = 0; t < 4; t++)
#pragma unroll
      for (int rg = 0; rg < 4; rg++) {
        int row = n0 + q * 4 + rg;
        float hv = hin[row * 64 + t * 16 + n16];
        float rr = hv + fmaxf(acc[t][rg] + nbv[t], 0.f);
        r[t][rg] = rr;
        p[rg] += rr;
        p2[rg] += rr * rr;
      }
#pragma unroll
    for (int rg = 0; rg < 4; rg++)
#pragma unroll
      for (int off = 1; off < 16; off <<= 1) {
        p[rg] += __shfl_xor(p[rg], off);
        p2[rg] += __shfl_xor(p2[rg], off);
      }
#pragma unroll
    for (int rg = 0; rg < 4; rg++) {
      float mu = p[rg] * (1.f / 64.f);
      float var = p2[rg] * (1.f / 64.f) - mu * mu;
      float rs = rsqrtf(fmaxf(var, 0.f) + 1e-5f);
      int row = n0 + q * 4 + rg;
#pragma unroll
      for (int t = 0; t < 4; t++) {
        float o = (r[t][rg] - mu) * rs * gv[t] + bv[t];
        hout[row * 64 + t * 16 + n16] = o;
        hbout[row * 64 + t * 16 + n16] = f2bf(o);
      }
    }
  }
}

// ---------- 5. head: out = relu(h@hw1+hb1)@hw2 + hb2 ----------
__global__ __launch_bounds__(256, 2) void k_head(const float* __restrict__ hw1,
                                                 const float* __restrict__ hb1,
                                                 const float* __restrict__ hw2,
                                                 const float* __restrict__ hb2,
                                                 const float* __restrict__ hin,
                                                 float* __restrict__ out) {
  int j = threadIdx.x & 63;
  int jj = j & 31;
  int gw = (blockIdx.x * 256 + threadIdx.x) >> 6;
  float w1[64];
#pragma unroll
  for (int k = 0; k < 64; k++) w1[k] = hw1[k * 32 + jj];
  float hb1j = hb1[jj];
  float hw2j = hw2[jj];
  float hb2v = hb2[0];
  int n0 = gw * NPW;
  for (int n = n0; n < n0 + NPW; ++n) {
    if (n >= N_NODES) break;
    float hv = hin[n * 64 + j];
    float acc = hb1j;
#pragma unroll
    for (int k = 0; k < 64; k++) acc += bcast(hv, k) * w1[k];
    float z = fmaxf(acc, 0.f) * hw2j;
    if (j >= 32) z = 0.f;
#pragma unroll
    for (int off = 32; off; off >>= 1) z += __shfl_xor(z, off);
    if (j == 0) out[n] = z + hb2v;
  }
}

// ---------- launch ----------
static inline size_t align256(size_t x) { return (x + 255) & ~size_t(255); }

extern "C" void kernel_launch(void* const* d_in, const int* in_sizes, int n_in,
                              void* d_out, int out_size, void* d_ws, size_t ws_size,
                              hipStream_t stream) {
  const float* x   = (const float*)d_in[0];
  const int*   ei  = (const int*)d_in[1];
  const float* ea  = (const float*)d_in[2];
  const float* Wp  = (const float*)d_in[3];
  const float* bp  = (const float*)d_in[4];
  const float* ew1 = (const float*)d_in[5];
  const float* eb1 = (const float*)d_in[6];
  const float* ew2 = (const float*)d_in[7];
  const float* eb2 = (const float*)d_in[8];
  const float* nw  = (const float*)d_in[9];
  const float* nb  = (const float*)d_in[10];
  const float* lng = (const float*)d_in[11];
  const float* lnb = (const float*)d_in[12];
  const float* hw1 = (const float*)d_in[13];
  const float* hb1 = (const float*)d_in[14];
  const float* hw2 = (const float*)d_in[15];
  const float* hb2 = (const float*)d_in[16];
  float* out = (float*)d_out;

  char* ws = (char*)d_ws;
  size_t off = 0;
  float* h0f = (float*)(ws + off); off = align256(off + (size_t)N_NODES * 64 * 4);
  float* h1f = (float*)(ws + off); off = align256(off + (size_t)N_NODES * 64 * 4);
  unsigned short* hb0  = (unsigned short*)(ws + off); off = align256(off + (size_t)N_NODES * 64 * 2);
  unsigned short* hb1b = (unsigned short*)(ws + off); off = align256(off + (size_t)N_NODES * 64 * 2);
  unsigned short* ab   = (unsigned short*)(ws + off); off = align256(off + (size_t)N_NODES * 64 * 2);
  uint2* csr = (uint2*)(ws + off); off = align256(off + (size_t)N_EDGES * 8);
  int* deg    = (int*)(ws + off); off = align256(off + (size_t)N_NODES * 4);
  int* offs   = (int*)(ws + off); off = align256(off + (size_t)N_NODES * 4);
  int* cursor = (int*)(ws + off); off = align256(off + (size_t)N_NODES * 4);
  int* bsums  = (int*)(ws + off); off = align256(off + 1024);

  const int NB_SCAN = (N_NODES + 255) / 256;  // 196

  hipMemsetAsync(deg, 0, (size_t)N_NODES * 4, stream);

  k_proj<<<(N_NODES * 64 + 255) / 256, 256, 0, stream>>>(x, Wp, bp, h0f, hb0);
  k_hist<<<(N_EDGES + 255) / 256, 256, 0, stream>>>(ei, deg);
  k_scan1<<<NB_SCAN, 256, 0, stream>>>(deg, offs, bsums);
  k_scan2<<<1, 256, 0, stream>>>(bsums, NB_SCAN);
  k_scan3<<<NB_SCAN, 256, 0, stream>>>(offs, bsums, cursor);

  const int nChunks = (N_EDGES + FILL_CHUNK - 1) / FILL_CHUNK;  // 391
  k_fill<<<nChunks * 8, 256, 0, stream>>>(ei, ea, ew1, eb1, ew2, eb2, cursor, csr);

  const int aggGrid = (N_NODES + 7) / 8;  // 4 nodes/wave, 4 waves/block
  const int mlpGrid = 392;
  const int headGrid = ((N_NODES + NPW - 1) / NPW + 3) / 4;

  // layer 0: h0 -> h1
  k_agg<0><<<aggGrid, 256, 0, stream>>>(csr, offs, deg, hb0, ab);
  k_mlp<<<mlpGrid, 256, 0, stream>>>(nw + 0 * 8192, nb + 0 * 64, lng + 0 * 64, lnb + 0 * 64,
                                     h0f, hb0, ab, h1f, hb1b);
  // layer 1: h1 -> h0
  k_agg<1><<<aggGrid, 256, 0, stream>>>(csr, offs, deg, hb1b, ab);
  k_mlp<<<mlpGrid, 256, 0, stream>>>(nw + 1 * 8192, nb + 1 * 64, lng + 1 * 64, lnb + 1 * 64,
                                     h1f, hb1b, ab, h0f, hb0);
  // layer 2: h0 -> h1
  k_agg<2><<<aggGrid, 256, 0, stream>>>(csr, offs, deg, hb0, ab);
  k_mlp<<<mlpGrid, 256, 0, stream>>>(nw + 2 * 8192, nb + 2 * 64, lng + 2 * 64, lnb + 2 * 64,
                                     h0f, hb0, ab, h1f, hb1b);

  k_head<<<headGrid, 256, 0, stream>>>(hw1, hb1, hw2, hb2, h1f, out);
}